// Round 6
// baseline (427.475 us; speedup 1.0000x reference)
//
#include <hip/hip_runtime.h>
#include <hip/hip_bf16.h>
#include <stdint.h>

#define FDIM 128
#define CDIM 10

typedef unsigned short u16;
typedef __attribute__((ext_vector_type(8))) short short8;   // 8 bf16 (4 VGPRs) — MFMA A/B frag
typedef __attribute__((ext_vector_type(4))) float f32x4;    // MFMA C/D frag

__device__ inline float bf2f(u16 b) {
    return __uint_as_float(((unsigned int)b) << 16);
}
__device__ inline u16 f2bf(float f) {
    unsigned int u = __float_as_uint(f);
    u += 0x7fff + ((u >> 16) & 1);  // round-to-nearest-even
    return (u16)(u >> 16);
}
__device__ inline unsigned int pack2(float a, float b) {
    return (unsigned int)f2bf(a) | ((unsigned int)f2bf(b) << 16);
}
// acc[0] += lo_bf16(u); acc[1] += hi_bf16(u)   (pure sum — tables are pre-scaled by dinv)
__device__ inline void add_bf2(float* acc, unsigned int u) {
    acc[0] += __uint_as_float(u << 16);
    acc[1] += __uint_as_float(u & 0xffff0000u);
}

// ---------------- utility ----------------

__global__ void zero_kernel(int* __restrict__ p, int n) {
    int i = blockIdx.x * blockDim.x + threadIdx.x;
    if (i < n) p[i] = 0;
}

__global__ void sentinel_kernel(float* __restrict__ out, int n, float val) {
    int i = blockIdx.x * blockDim.x + threadIdx.x;
    if (i < n) out[i] = val;
}

// W [128][128] fp32 -> WbT [n][k] bf16 (transposed), for 3 weight matrices
__global__ void wconv_kernel(const float* __restrict__ W1, const float* __restrict__ W2,
                             const float* __restrict__ W3, u16* __restrict__ wbt) {
    int which = blockIdx.x >> 6;
    int i = (blockIdx.x & 63) * 256 + threadIdx.x;
    const float* W = which == 0 ? W1 : (which == 1 ? W2 : W3);
    int k = i >> 7, n = i & 127;
    wbt[(size_t)which * 16384 + n * 128 + k] = f2bf(W[k * 128 + n]);
}

// x fp32 -> bf16 pre-scaled by dinv; also zeroes row N (the tail-mask zero row)
__global__ void xconv_kernel(const float* __restrict__ x, const float* __restrict__ dinv,
                             u16* __restrict__ xb, int N) {
    int i = (blockIdx.x * blockDim.x + threadIdx.x) * 4;
    int total = N * FDIM;
    if (i < total) {
        int v = i >> 7;
        float dv = dinv[v];
        float4 f = *(const float4*)&x[i];
        uint2 o;
        o.x = pack2(dv * f.x, dv * f.y);
        o.y = pack2(dv * f.z, dv * f.w);
        *(uint2*)&xb[i] = o;
    } else if (i < total + FDIM) {
        *(uint2*)&xb[i] = make_uint2(0, 0);  // zero row N
    }
}

// ---------------- bucketed CSR build ----------------
// buckets of 256 nodes: b = dst >> 8.  NB = ceil(N/256) <= 512.
// ebuf entry packed: (dst & 255) << 24 | src   (requires N <= 2^24)

__global__ __launch_bounds__(256) void count_kernel(const int* __restrict__ dst, int E,
                                                    int* __restrict__ bcnt, int NB) {
    __shared__ int lc[512];
    int tid = threadIdx.x;
    for (int i = tid; i < NB; i += 256) lc[i] = 0;
    __syncthreads();
    int base = blockIdx.x * 4096;
    int lim = min(base + 4096, E);
    for (int i = base + tid; i < lim; i += 256)
        atomicAdd(&lc[dst[i] >> 8], 1);
    __syncthreads();
    for (int i = tid; i < NB; i += 256)
        if (lc[i]) atomicAdd(&bcnt[i], lc[i]);
}

__global__ __launch_bounds__(512) void scan_kernel(const int* __restrict__ bcnt, int NB, int E,
                                                   int* __restrict__ boff, int* __restrict__ bcursor) {
    __shared__ int s[512];
    int tid = threadIdx.x;
    s[tid] = (tid < NB) ? bcnt[tid] : 0;
    __syncthreads();
    for (int off = 1; off < 512; off <<= 1) {
        int v = (tid >= off) ? s[tid - off] : 0;
        __syncthreads();
        s[tid] += v;
        __syncthreads();
    }
    int excl = tid ? s[tid - 1] : 0;
    if (tid < NB) { boff[tid] = excl; bcursor[tid] = excl; }
    if (tid == 0) boff[NB] = E;
}

__global__ __launch_bounds__(256) void part_kernel(const int* __restrict__ src,
                                                   const int* __restrict__ dst, int E,
                                                   int* __restrict__ bcursor,
                                                   unsigned* __restrict__ ebuf, int NB) {
    __shared__ int lc[512];
    __shared__ int lbase[512];
    int tid = threadIdx.x;
    for (int i = tid; i < NB; i += 256) lc[i] = 0;
    __syncthreads();
    int base = blockIdx.x * 4096;
    int lim = min(base + 4096, E);
    for (int i = base + tid; i < lim; i += 256)
        atomicAdd(&lc[dst[i] >> 8], 1);
    __syncthreads();
    for (int i = tid; i < NB; i += 256) {
        int c = lc[i];
        lbase[i] = c ? atomicAdd(&bcursor[i], c) : 0;
        lc[i] = 0;  // reuse as local cursor
    }
    __syncthreads();
    for (int i = base + tid; i < lim; i += 256) {
        int s_ = src[i];
        int d_ = dst[i];
        int b = d_ >> 8;
        int r = atomicAdd(&lc[b], 1);
        ebuf[lbase[b] + r] = ((unsigned)(d_ & 255) << 24) | (unsigned)s_;
    }
}

// one block per bucket: local hist -> scan -> rowp/deg/dinv; scatter colx within bucket window
__global__ __launch_bounds__(256) void build_kernel(const unsigned* __restrict__ ebuf,
                                                    const int* __restrict__ boff,
                                                    int* __restrict__ rowp, float* __restrict__ dinv,
                                                    int* __restrict__ colx, int N, int E) {
    __shared__ int hist[256];
    __shared__ int pfx[256];
    __shared__ int cur[256];
    int b = blockIdx.x;
    int tid = threadIdx.x;
    int ebase = boff[b], eend = boff[b + 1];
    hist[tid] = 0;
    __syncthreads();
    for (int i = ebase + tid; i < eend; i += 256)
        atomicAdd(&hist[ebuf[i] >> 24], 1);
    __syncthreads();
    int deg = hist[tid];
    pfx[tid] = deg;
    __syncthreads();
    for (int off = 1; off < 256; off <<= 1) {
        int t = (tid >= off) ? pfx[tid - off] : 0;
        __syncthreads();
        pfx[tid] += t;
        __syncthreads();
    }
    int excl = pfx[tid] - deg;
    int node = b * 256 + tid;
    if (node < N) {
        rowp[node] = ebase + excl;
        dinv[node] = rsqrtf(1.0f + (float)deg);  // +1 self-loop
        if (node == N - 1) rowp[N] = E;
    }
    cur[tid] = ebase + excl;
    __syncthreads();
    for (int i = ebase + tid; i < eend; i += 256) {
        unsigned e = ebuf[i];
        int r = atomicAdd(&cur[e >> 24], 1);
        colx[r] = (int)(e & 0xFFFFFFu);
    }
}

// ---------------- fused layer: agg (pre-scaled sum gather) -> LDS -> MFMA GEMM -> epilogue ----------------
// hs_in: (N+1) x 128 bf16, row v = dinv[v]*h[v], row N = zeros (tail mask target).
// agg row v = dinv[v]*(hs[v] + sum_{u->v} hs[u])   -> LDS As[64][136] bf16
// gemm: out = relu(As @ W + b); SCALE ? *dinv (next layer's pre-scaled table) : raw (final h3).
// Wave w owns nodes/rows [w*16, w*16+16) of the block tile — gather, LDS write, and MFMA A-frag
// all stay within the wave; single barrier for safety.

template <bool SCALE>
__global__ __launch_bounds__(256) void fused_layer_kernel(const u16* __restrict__ hs_in,
                                                          const int* __restrict__ rowp,
                                                          const int* __restrict__ colx,
                                                          const float* __restrict__ dinv,
                                                          const u16* __restrict__ WbT,
                                                          const float* __restrict__ bias,
                                                          u16* __restrict__ out, int N) {
    __shared__ u16 As[64][136];
    int tid = threadIdx.x;
    int w = tid >> 6;
    int l = tid & 63;
    int g = l >> 4;
    int c = l & 15;
    int row0 = blockIdx.x * 64;

    const uint4* h4 = (const uint4*)hs_in;

    // ---- phase 1: gather 16 rows for this wave ----
    for (int i = 0; i < 16; ++i) {
        int v = row0 + w * 16 + i;
        if (v < N) {
            v = __builtin_amdgcn_readfirstlane(v);
            int e0 = rowp[v], end = rowp[v + 1];
            float acc[8];
#pragma unroll
            for (int j = 0; j < 8; ++j) acc[j] = 0.f;

            for (int e = e0; e < end; e += 16) {
                int i0 = e + g, i1 = e + 4 + g, i2 = e + 8 + g, i3 = e + 12 + g;
                int u0 = (i0 < end) ? colx[i0] : N;
                int u1 = (i1 < end) ? colx[i1] : N;
                int u2 = (i2 < end) ? colx[i2] : N;
                int u3 = (i3 < end) ? colx[i3] : N;
                uint4 r0 = h4[(size_t)u0 * 16 + c];
                uint4 r1 = h4[(size_t)u1 * 16 + c];
                uint4 r2 = h4[(size_t)u2 * 16 + c];
                uint4 r3 = h4[(size_t)u3 * 16 + c];
                add_bf2(acc + 0, r0.x); add_bf2(acc + 2, r0.y); add_bf2(acc + 4, r0.z); add_bf2(acc + 6, r0.w);
                add_bf2(acc + 0, r1.x); add_bf2(acc + 2, r1.y); add_bf2(acc + 4, r1.z); add_bf2(acc + 6, r1.w);
                add_bf2(acc + 0, r2.x); add_bf2(acc + 2, r2.y); add_bf2(acc + 4, r2.z); add_bf2(acc + 6, r2.w);
                add_bf2(acc + 0, r3.x); add_bf2(acc + 2, r3.y); add_bf2(acc + 4, r3.z); add_bf2(acc + 6, r3.w);
            }

#pragma unroll
            for (int j = 0; j < 8; ++j) {
                acc[j] += __shfl_xor(acc[j], 16, 64);
                acc[j] += __shfl_xor(acc[j], 32, 64);
            }

            if (g == 0) {
                uint4 s = h4[(size_t)v * 16 + c];
                add_bf2(acc + 0, s.x); add_bf2(acc + 2, s.y); add_bf2(acc + 4, s.z); add_bf2(acc + 6, s.w);
                float dv = dinv[v];
                uint4 o;
                o.x = pack2(dv * acc[0], dv * acc[1]);
                o.y = pack2(dv * acc[2], dv * acc[3]);
                o.z = pack2(dv * acc[4], dv * acc[5]);
                o.w = pack2(dv * acc[6], dv * acc[7]);
                *(uint4*)&As[w * 16 + i][c * 8] = o;
            }
        }
    }
    __syncthreads();

    // ---- phase 2: MFMA GEMM on the tile ----
    int arow = w * 16 + (l & 15);
    int kblk = (l >> 4) * 8;
    f32x4 facc[8];
#pragma unroll
    for (int f = 0; f < 8; ++f) facc[f] = (f32x4){0.f, 0.f, 0.f, 0.f};

#pragma unroll
    for (int kk = 0; kk < 4; ++kk) {
        int k0 = kk * 32 + kblk;
        short8 a = *(const short8*)&As[arow][k0];
#pragma unroll
        for (int f = 0; f < 8; ++f) {
            int col = f * 16 + (l & 15);
            short8 bfr = *(const short8*)&WbT[(size_t)col * FDIM + k0];
            facc[f] = __builtin_amdgcn_mfma_f32_16x16x32_bf16(a, bfr, facc[f], 0, 0, 0);
        }
    }

    int rbase = w * 16 + (l >> 4) * 4;
    int cidx = l & 15;
    float dvr[4];
#pragma unroll
    for (int r = 0; r < 4; ++r) {
        int row = row0 + rbase + r;
        dvr[r] = (SCALE && row < N) ? dinv[row] : 1.f;
    }
#pragma unroll
    for (int f = 0; f < 8; ++f) {
        int col = f * 16 + cidx;
        float bv = bias[col];
#pragma unroll
        for (int r = 0; r < 4; ++r) {
            int row = row0 + rbase + r;
            if (row < N) {
                float val = fmaxf(facc[f][r] + bv, 0.f);
                if (SCALE) val *= dvr[r];
                out[(size_t)row * FDIM + col] = f2bf(val);
            }
        }
    }
}

// ---------------- pooling + classifier head + log_softmax ----------------

__global__ __launch_bounds__(256) void pool_head_kernel(const u16* __restrict__ h,
                                                        const int* __restrict__ batch, int N,
                                                        const float* __restrict__ Wo,
                                                        const float* __restrict__ bo,
                                                        float* __restrict__ out, int G) {
    int g = blockIdx.x;
    int tid = threadIdx.x;
    __shared__ int bounds[2];
    __shared__ float red[256];
    __shared__ float sp[128];
    __shared__ float lg[CDIM];
    __shared__ float sm[2];

    if (tid < 2) {
        int target = g + tid;
        int lo = 0, hi = N;
        while (lo < hi) {
            int mid = (lo + hi) >> 1;
            if (batch[mid] < target) lo = mid + 1; else hi = mid;
        }
        bounds[tid] = lo;
    }
    __syncthreads();
    int lo = bounds[0], hi = bounds[1];
    int cnt = hi - lo;

    int j = tid & 127;
    int rr = tid >> 7;
    float acc = 0.f;
    for (int r = lo + rr; r < hi; r += 2) acc += bf2f(h[(size_t)r * FDIM + j]);
    red[tid] = acc;
    __syncthreads();
    if (tid < 128) sp[tid] = (red[tid] + red[tid + 128]) / (float)max(cnt, 1);
    __syncthreads();

    if (tid < CDIM) {
        float l = bo[tid];
        for (int k = 0; k < 128; ++k) l += sp[k] * Wo[(size_t)k * CDIM + tid];
        lg[tid] = l;
    }
    __syncthreads();
    if (tid == 0) {
        float m = -1e30f;
        for (int c = 0; c < CDIM; ++c) m = fmaxf(m, lg[c]);
        float ssum = 0.f;
        for (int c = 0; c < CDIM; ++c) ssum += expf(lg[c] - m);
        sm[0] = m;
        sm[1] = logf(ssum);
    }
    __syncthreads();
    if (tid < CDIM) out[(size_t)g * CDIM + tid] = lg[tid] - sm[0] - sm[1];
}

// ---------------- launch ----------------

extern "C" void kernel_launch(void* const* d_in, const int* in_sizes, int n_in,
                              void* d_out, int out_size, void* d_ws, size_t ws_size,
                              hipStream_t stream) {
    const float* x = (const float*)d_in[0];
    const int* edge = (const int*)d_in[1];      // int32 (harness converts integer inputs)
    const int* batch = (const int*)d_in[2];     // int32
    const float* W1 = (const float*)d_in[4];
    const float* b1 = (const float*)d_in[5];
    const float* W2 = (const float*)d_in[6];
    const float* b2 = (const float*)d_in[7];
    const float* W3 = (const float*)d_in[8];
    const float* b3 = (const float*)d_in[9];
    const float* Wo = (const float*)d_in[10];
    const float* bo = (const float*)d_in[11];

    int N = in_sizes[2];
    int E = in_sizes[1] / 2;
    int G = out_size / CDIM;
    const int* src = edge;
    const int* dst = edge + E;
    int NB = (N + 255) >> 8;

    size_t off = 0;
    auto carve = [&](size_t bytes) -> size_t {
        size_t r = off;
        off += (bytes + 255) & ~(size_t)255;
        return r;
    };
    size_t hs_bytes = (size_t)(N + 1) * FDIM * 2;   // N+1 rows: row N is the zero row
    size_t o_hsA = carve(hs_bytes);                 // ebuf aliases here during CSR build
    size_t o_hsB = carve(hs_bytes);
    size_t o_colx = carve((size_t)E * 4);
    size_t o_rowp = carve((size_t)(N + 1) * 4);
    size_t o_dinv = carve((size_t)N * 4);
    size_t o_bcnt = carve((size_t)NB * 4);
    size_t o_boff = carve((size_t)(NB + 1) * 4);
    size_t o_bcur = carve((size_t)NB * 4);
    size_t o_wbt  = carve((size_t)3 * 16384 * 2);

    bool ok = off <= ws_size && NB <= 512 && N <= (1 << 24) &&
              (size_t)E * 4 <= hs_bytes;  // packed ebuf fits in hsA alias
    if (!ok) {
        sentinel_kernel<<<(out_size + 255) / 256, 256, 0, stream>>>((float*)d_out, out_size, 1234.5f);
        return;
    }

    char* base = (char*)d_ws;
    u16* hsA   = (u16*)(base + o_hsA);
    u16* hsB   = (u16*)(base + o_hsB);
    unsigned* ebuf = (unsigned*)(base + o_hsA);  // alias (dead after build_kernel, before xconv)
    int* colx  = (int*)(base + o_colx);
    int* rowp  = (int*)(base + o_rowp);
    float* dinv = (float*)(base + o_dinv);
    int* bcnt  = (int*)(base + o_bcnt);
    int* boff  = (int*)(base + o_boff);
    int* bcur  = (int*)(base + o_bcur);
    u16* wbt   = (u16*)(base + o_wbt);

    int nchunk = (E + 4095) / 4096;

    wconv_kernel<<<192, 256, 0, stream>>>(W1, W2, W3, wbt);
    zero_kernel<<<1, 512, 0, stream>>>(bcnt, NB);
    zero_kernel<<<1, 64, 0, stream>>>((int*)(hsB + (size_t)N * FDIM), FDIM / 2);  // zero row N of hsB
    count_kernel<<<nchunk, 256, 0, stream>>>(dst, E, bcnt, NB);
    scan_kernel<<<1, 512, 0, stream>>>(bcnt, NB, E, boff, bcur);
    part_kernel<<<nchunk, 256, 0, stream>>>(src, dst, E, bcur, ebuf, NB);
    build_kernel<<<NB, 256, 0, stream>>>(ebuf, boff, rowp, dinv, colx, N, E);
    xconv_kernel<<<(((N + 1) * FDIM / 4) + 255) / 256, 256, 0, stream>>>(x, dinv, hsA, N);

    int layerBlocks = (N + 63) / 64;

    // L1: hsA (pre-scaled x) -> hsB (pre-scaled h1)
    fused_layer_kernel<true><<<layerBlocks, 256, 0, stream>>>(hsA, rowp, colx, dinv, wbt, b1, hsB, N);
    // L2: hsB -> hsA (pre-scaled h2)
    fused_layer_kernel<true><<<layerBlocks, 256, 0, stream>>>(hsB, rowp, colx, dinv, wbt + 16384, b2, hsA, N);
    // L3: hsA -> hsB (UNscaled h3, for pooling)
    fused_layer_kernel<false><<<layerBlocks, 256, 0, stream>>>(hsA, rowp, colx, dinv, wbt + 32768, b3, hsB, N);

    pool_head_kernel<<<G, 256, 0, stream>>>(hsB, batch, N, Wo, bo, (float*)d_out, G);
}

// Round 7
// 363.547 us; speedup vs baseline: 1.1758x; 1.1758x over previous
//
#include <hip/hip_runtime.h>
#include <hip/hip_bf16.h>
#include <stdint.h>

#define FDIM 128
#define CDIM 10

typedef unsigned short u16;
typedef __attribute__((ext_vector_type(8))) short short8;   // 8 bf16 (4 VGPRs) — MFMA A/B frag
typedef __attribute__((ext_vector_type(4))) float f32x4;    // MFMA C/D frag

__device__ inline float bf2f(u16 b) {
    return __uint_as_float(((unsigned int)b) << 16);
}
__device__ inline u16 f2bf(float f) {
    unsigned int u = __float_as_uint(f);
    u += 0x7fff + ((u >> 16) & 1);  // round-to-nearest-even
    return (u16)(u >> 16);
}
__device__ inline unsigned int pack2(float a, float b) {
    return (unsigned int)f2bf(a) | ((unsigned int)f2bf(b) << 16);
}
// acc[0] += lo_bf16(u); acc[1] += hi_bf16(u)   (pure sum — tables pre-scaled by dinv)
__device__ inline void add_bf2(float* acc, unsigned int u) {
    acc[0] += __uint_as_float(u << 16);
    acc[1] += __uint_as_float(u & 0xffff0000u);
}

// ---------------- utility ----------------

__global__ void sentinel_kernel(float* __restrict__ out, int n, float val) {
    int i = blockIdx.x * blockDim.x + threadIdx.x;
    if (i < n) out[i] = val;
}

// W [128][128] fp32 -> WbT [n][k] bf16 (transposed) for 3 matrices; also zeroes
// hsB row N and bcnt (merged to save launches).
__global__ void wconv_kernel(const float* __restrict__ W1, const float* __restrict__ W2,
                             const float* __restrict__ W3, u16* __restrict__ wbt,
                             unsigned* __restrict__ hsB_rowN, int* __restrict__ bcnt, int NB) {
    int tid = threadIdx.x;
    if (blockIdx.x == 192) {
        if (tid < FDIM / 2) hsB_rowN[tid] = 0;
        return;
    }
    if (blockIdx.x == 193) {
        for (int i = tid; i < NB; i += 256) bcnt[i] = 0;
        return;
    }
    int which = blockIdx.x >> 6;
    int i = (blockIdx.x & 63) * 256 + tid;
    const float* W = which == 0 ? W1 : (which == 1 ? W2 : W3);
    int k = i >> 7, n = i & 127;
    wbt[(size_t)which * 16384 + n * 128 + k] = f2bf(W[k * 128 + n]);
}

// x fp32 -> bf16 pre-scaled by dinv; also zeroes row N (tail-mask target)
__global__ void xconv_kernel(const float* __restrict__ x, const float* __restrict__ dinv,
                             u16* __restrict__ xb, int N) {
    int i = (blockIdx.x * blockDim.x + threadIdx.x) * 4;
    int total = N * FDIM;
    if (i < total) {
        int v = i >> 7;
        float dv = dinv[v];
        float4 f = *(const float4*)&x[i];
        uint2 o;
        o.x = pack2(dv * f.x, dv * f.y);
        o.y = pack2(dv * f.z, dv * f.w);
        *(uint2*)&xb[i] = o;
    } else if (i < total + FDIM) {
        *(uint2*)&xb[i] = make_uint2(0, 0);  // zero row N
    }
}

// ---------------- bucketed CSR build ----------------
// buckets of 256 nodes: b = dst >> 8.  NB = ceil(N/256) <= 512.
// ebuf entry packed: (dst & 255) << 24 | src   (requires N <= 2^24)

__global__ __launch_bounds__(256) void count_kernel(const int* __restrict__ dst, int E,
                                                    int* __restrict__ bcnt, int NB) {
    __shared__ int lc[512];
    int tid = threadIdx.x;
    for (int i = tid; i < NB; i += 256) lc[i] = 0;
    __syncthreads();
    int base = blockIdx.x * 4096;
    int lim = min(base + 4096, E);
    for (int i = base + tid; i < lim; i += 256)
        atomicAdd(&lc[dst[i] >> 8], 1);
    __syncthreads();
    for (int i = tid; i < NB; i += 256)
        if (lc[i]) atomicAdd(&bcnt[i], lc[i]);
}

__global__ __launch_bounds__(512) void scan_kernel(const int* __restrict__ bcnt, int NB, int E,
                                                   int* __restrict__ boff, int* __restrict__ bcursor) {
    __shared__ int s[512];
    int tid = threadIdx.x;
    s[tid] = (tid < NB) ? bcnt[tid] : 0;
    __syncthreads();
    for (int off = 1; off < 512; off <<= 1) {
        int v = (tid >= off) ? s[tid - off] : 0;
        __syncthreads();
        s[tid] += v;
        __syncthreads();
    }
    int excl = tid ? s[tid - 1] : 0;
    if (tid < NB) { boff[tid] = excl; bcursor[tid] = excl; }
    if (tid == 0) boff[NB] = E;
}

__global__ __launch_bounds__(256) void part_kernel(const int* __restrict__ src,
                                                   const int* __restrict__ dst, int E,
                                                   int* __restrict__ bcursor,
                                                   unsigned* __restrict__ ebuf, int NB) {
    __shared__ int lc[512];
    __shared__ int lbase[512];
    int tid = threadIdx.x;
    for (int i = tid; i < NB; i += 256) lc[i] = 0;
    __syncthreads();
    int base = blockIdx.x * 4096;
    int lim = min(base + 4096, E);
    for (int i = base + tid; i < lim; i += 256)
        atomicAdd(&lc[dst[i] >> 8], 1);
    __syncthreads();
    for (int i = tid; i < NB; i += 256) {
        int c = lc[i];
        lbase[i] = c ? atomicAdd(&bcursor[i], c) : 0;
        lc[i] = 0;  // reuse as local cursor
    }
    __syncthreads();
    for (int i = base + tid; i < lim; i += 256) {
        int s_ = src[i];
        int d_ = dst[i];
        int b = d_ >> 8;
        int r = atomicAdd(&lc[b], 1);
        ebuf[lbase[b] + r] = ((unsigned)(d_ & 255) << 24) | (unsigned)s_;
    }
}

// one block per bucket: local hist -> scan -> rowp/deg/dinv; scatter colx within bucket window
__global__ __launch_bounds__(256) void build_kernel(const unsigned* __restrict__ ebuf,
                                                    const int* __restrict__ boff,
                                                    int* __restrict__ rowp, float* __restrict__ dinv,
                                                    int* __restrict__ colx, int N, int E) {
    __shared__ int hist[256];
    __shared__ int pfx[256];
    __shared__ int cur[256];
    int b = blockIdx.x;
    int tid = threadIdx.x;
    int ebase = boff[b], eend = boff[b + 1];
    hist[tid] = 0;
    __syncthreads();
    for (int i = ebase + tid; i < eend; i += 256)
        atomicAdd(&hist[ebuf[i] >> 24], 1);
    __syncthreads();
    int deg = hist[tid];
    pfx[tid] = deg;
    __syncthreads();
    for (int off = 1; off < 256; off <<= 1) {
        int t = (tid >= off) ? pfx[tid - off] : 0;
        __syncthreads();
        pfx[tid] += t;
        __syncthreads();
    }
    int excl = pfx[tid] - deg;
    int node = b * 256 + tid;
    if (node < N) {
        rowp[node] = ebase + excl;
        dinv[node] = rsqrtf(1.0f + (float)deg);  // +1 self-loop
        if (node == N - 1) rowp[N] = E;
    }
    cur[tid] = ebase + excl;
    __syncthreads();
    for (int i = ebase + tid; i < eend; i += 256) {
        unsigned e = ebuf[i];
        int r = atomicAdd(&cur[e >> 24], 1);
        colx[r] = (int)(e & 0xFFFFFFu);
    }
}

// ---------------- aggregation (pre-scaled tables) ----------------
// out[v] = dinv[v]*(hs[v] + sum_{u->v} hs[u]); hs has zero row N for tail masking.
// wave/node; lane = 16*g + c: group g walks edges e+g, e+4+g, e+8+g, e+12+g (4 uint4 in flight);
// lane covers cols [8c, 8c+8) (16B). Cross-group combine via 2x shfl_xor.

__global__ __launch_bounds__(256) void agg_kernel(const u16* __restrict__ hs,
                                                  const float* __restrict__ dinv,
                                                  const int* __restrict__ rowp,
                                                  const int* __restrict__ colx,
                                                  u16* __restrict__ out, int N) {
    int wib = threadIdx.x >> 6;
    int lane = threadIdx.x & 63;
    int g = lane >> 4;
    int c = lane & 15;
    int v = blockIdx.x * 4 + wib;
    if (v >= N) return;
    v = __builtin_amdgcn_readfirstlane(v);

    const uint4* h4 = (const uint4*)hs;
    float acc[8];
#pragma unroll
    for (int j = 0; j < 8; ++j) acc[j] = 0.f;

    int e0 = rowp[v], end = rowp[v + 1];
    for (int e = e0; e < end; e += 16) {
        int i0 = e + g, i1 = e + 4 + g, i2 = e + 8 + g, i3 = e + 12 + g;
        int u0 = (i0 < end) ? colx[i0] : N;
        int u1 = (i1 < end) ? colx[i1] : N;
        int u2 = (i2 < end) ? colx[i2] : N;
        int u3 = (i3 < end) ? colx[i3] : N;
        uint4 r0 = h4[(size_t)u0 * 16 + c];
        uint4 r1 = h4[(size_t)u1 * 16 + c];
        uint4 r2 = h4[(size_t)u2 * 16 + c];
        uint4 r3 = h4[(size_t)u3 * 16 + c];
        add_bf2(acc + 0, r0.x); add_bf2(acc + 2, r0.y); add_bf2(acc + 4, r0.z); add_bf2(acc + 6, r0.w);
        add_bf2(acc + 0, r1.x); add_bf2(acc + 2, r1.y); add_bf2(acc + 4, r1.z); add_bf2(acc + 6, r1.w);
        add_bf2(acc + 0, r2.x); add_bf2(acc + 2, r2.y); add_bf2(acc + 4, r2.z); add_bf2(acc + 6, r2.w);
        add_bf2(acc + 0, r3.x); add_bf2(acc + 2, r3.y); add_bf2(acc + 4, r3.z); add_bf2(acc + 6, r3.w);
    }

#pragma unroll
    for (int j = 0; j < 8; ++j) {
        acc[j] += __shfl_xor(acc[j], 16, 64);
        acc[j] += __shfl_xor(acc[j], 32, 64);
    }

    if (g == 0) {
        uint4 s = h4[(size_t)v * 16 + c];
        add_bf2(acc + 0, s.x); add_bf2(acc + 2, s.y); add_bf2(acc + 4, s.z); add_bf2(acc + 6, s.w);
        float dv = dinv[v];
        uint4 o;
        o.x = pack2(dv * acc[0], dv * acc[1]);
        o.y = pack2(dv * acc[2], dv * acc[3]);
        o.z = pack2(dv * acc[4], dv * acc[5]);
        o.w = pack2(dv * acc[6], dv * acc[7]);
        ((uint4*)out)[(size_t)v * 16 + c] = o;
    }
}

// ---------------- in-place MFMA GEMM: buf = epilogue(buf @ W + b) ----------------
// Each block stages its own 64 rows into LDS BEFORE overwriting them -> in-place is safe
// (no cross-block row sharing). Epilogue: SCALE ? dinv*relu(.) (next pre-scaled table)
// : relu(.) (final h3). Results staged to LDS, stored as coalesced uint4 rows.

template <bool SCALE>
__global__ __launch_bounds__(256) void gemm_mfma_kernel(u16* __restrict__ buf,
                                                        const u16* __restrict__ WbT,
                                                        const float* __restrict__ bias,
                                                        const float* __restrict__ dinv, int N) {
    __shared__ u16 As[64][136];
    int tid = threadIdx.x;
    int w = tid >> 6;
    int l = tid & 63;
    int row0 = blockIdx.x * 64;

    // stage A tile (64 x 128 bf16)
#pragma unroll
    for (int i = 0; i < 4; ++i) {
        int ch = tid + 256 * i;
        int r = ch >> 4;
        int col = (ch & 15) * 8;
        uint4 val = make_uint4(0, 0, 0, 0);
        if (row0 + r < N) val = *(const uint4*)&buf[(size_t)(row0 + r) * FDIM + col];
        *(uint4*)&As[r][col] = val;
    }
    __syncthreads();

    int arow = w * 16 + (l & 15);
    int kblk = (l >> 4) * 8;
    f32x4 facc[8];
#pragma unroll
    for (int f = 0; f < 8; ++f) facc[f] = (f32x4){0.f, 0.f, 0.f, 0.f};

#pragma unroll
    for (int kk = 0; kk < 4; ++kk) {
        int k0 = kk * 32 + kblk;
        short8 a = *(const short8*)&As[arow][k0];
#pragma unroll
        for (int f = 0; f < 8; ++f) {
            int col = f * 16 + (l & 15);
            short8 bfr = *(const short8*)&WbT[(size_t)col * FDIM + k0];
            facc[f] = __builtin_amdgcn_mfma_f32_16x16x32_bf16(a, bfr, facc[f], 0, 0, 0);
        }
    }
    __syncthreads();  // all ds_reads of As done before overwrite

    // epilogue -> stage bf16 results back into As (each wave touches only its own rows)
    int rbase = w * 16 + (l >> 4) * 4;
    int cidx = l & 15;
    float dvr[4];
#pragma unroll
    for (int r = 0; r < 4; ++r) {
        int row = row0 + rbase + r;
        dvr[r] = (SCALE && row < N) ? dinv[row] : 1.f;
    }
#pragma unroll
    for (int f = 0; f < 8; ++f) {
        int col = f * 16 + cidx;
        float bv = bias[col];
#pragma unroll
        for (int r = 0; r < 4; ++r) {
            float val = fmaxf(facc[f][r] + bv, 0.f);
            if (SCALE) val *= dvr[r];
            As[rbase + r][col] = f2bf(val);
        }
    }
    __syncthreads();

    // coalesced store of the 64x128 tile
#pragma unroll
    for (int i = 0; i < 4; ++i) {
        int ch = tid + 256 * i;
        int r = ch >> 4;
        int col = (ch & 15) * 8;
        if (row0 + r < N) *(uint4*)&buf[(size_t)(row0 + r) * FDIM + col] = *(const uint4*)&As[r][col];
    }
}

// ---------------- pooling + classifier head + log_softmax ----------------
// one block (512 thr) per graph; batch sorted int32; 8 rows in flight, 4B/lane loads.

__global__ __launch_bounds__(512) void pool_head_kernel(const u16* __restrict__ h,
                                                        const int* __restrict__ batch, int N,
                                                        const float* __restrict__ Wo,
                                                        const float* __restrict__ bo,
                                                        float* __restrict__ out, int G) {
    int g = blockIdx.x;
    int tid = threadIdx.x;
    __shared__ int bounds[2];
    __shared__ float2 red[512];
    __shared__ float sp[128];
    __shared__ float lg[CDIM];
    __shared__ float sm[2];

    if (tid < 2) {
        int target = g + tid;
        int lo = 0, hi = N;
        while (lo < hi) {
            int mid = (lo + hi) >> 1;
            if (batch[mid] < target) lo = mid + 1; else hi = mid;
        }
        bounds[tid] = lo;
    }
    __syncthreads();
    int lo = bounds[0], hi = bounds[1];
    int cnt = hi - lo;

    int j = tid & 63;        // uint index within row (2 cols)
    int rg = tid >> 6;       // 0..7: eight rows in flight
    const unsigned* h2 = (const unsigned*)h;
    float ax = 0.f, ay = 0.f;
    for (int r = lo + rg; r < hi; r += 8) {
        unsigned u = h2[(size_t)r * 64 + j];
        ax += __uint_as_float(u << 16);
        ay += __uint_as_float(u & 0xffff0000u);
    }
    red[tid] = make_float2(ax, ay);
    __syncthreads();
    if (tid < 64) {
        float sx = 0.f, sy = 0.f;
#pragma unroll
        for (int k = 0; k < 8; ++k) {
            float2 t = red[tid + 64 * k];
            sx += t.x; sy += t.y;
        }
        float inv = 1.f / (float)max(cnt, 1);
        sp[2 * tid] = sx * inv;
        sp[2 * tid + 1] = sy * inv;
    }
    __syncthreads();

    if (tid < CDIM) {
        float l = bo[tid];
        for (int k = 0; k < 128; ++k) l += sp[k] * Wo[(size_t)k * CDIM + tid];
        lg[tid] = l;
    }
    __syncthreads();
    if (tid == 0) {
        float m = -1e30f;
        for (int c = 0; c < CDIM; ++c) m = fmaxf(m, lg[c]);
        float ssum = 0.f;
        for (int c = 0; c < CDIM; ++c) ssum += expf(lg[c] - m);
        sm[0] = m;
        sm[1] = logf(ssum);
    }
    __syncthreads();
    if (tid < CDIM) out[(size_t)g * CDIM + tid] = lg[tid] - sm[0] - sm[1];
}

// ---------------- launch ----------------

extern "C" void kernel_launch(void* const* d_in, const int* in_sizes, int n_in,
                              void* d_out, int out_size, void* d_ws, size_t ws_size,
                              hipStream_t stream) {
    const float* x = (const float*)d_in[0];
    const int* edge = (const int*)d_in[1];      // int32 (harness converts integer inputs)
    const int* batch = (const int*)d_in[2];     // int32
    const float* W1 = (const float*)d_in[4];
    const float* b1 = (const float*)d_in[5];
    const float* W2 = (const float*)d_in[6];
    const float* b2 = (const float*)d_in[7];
    const float* W3 = (const float*)d_in[8];
    const float* b3 = (const float*)d_in[9];
    const float* Wo = (const float*)d_in[10];
    const float* bo = (const float*)d_in[11];

    int N = in_sizes[2];
    int E = in_sizes[1] / 2;
    int G = out_size / CDIM;
    const int* src = edge;
    const int* dst = edge + E;
    int NB = (N + 255) >> 8;

    size_t off = 0;
    auto carve = [&](size_t bytes) -> size_t {
        size_t r = off;
        off += (bytes + 255) & ~(size_t)255;
        return r;
    };
    size_t hs_bytes = (size_t)(N + 1) * FDIM * 2;   // N+1 rows: row N = zeros
    size_t o_hsA = carve(hs_bytes);                 // ebuf aliases here during CSR build
    size_t o_hsB = carve(hs_bytes);
    size_t o_colx = carve((size_t)E * 4);
    size_t o_rowp = carve((size_t)(N + 1) * 4);
    size_t o_dinv = carve((size_t)N * 4);
    size_t o_bcnt = carve((size_t)NB * 4);
    size_t o_boff = carve((size_t)(NB + 1) * 4);
    size_t o_bcur = carve((size_t)NB * 4);
    size_t o_wbt  = carve((size_t)3 * 16384 * 2);

    bool ok = off <= ws_size && NB <= 512 && N <= (1 << 24) &&
              (size_t)E * 4 <= hs_bytes;  // packed ebuf fits in hsA alias
    if (!ok) {
        sentinel_kernel<<<(out_size + 255) / 256, 256, 0, stream>>>((float*)d_out, out_size, 1234.5f);
        return;
    }

    char* base = (char*)d_ws;
    u16* hsA   = (u16*)(base + o_hsA);
    u16* hsB   = (u16*)(base + o_hsB);
    unsigned* ebuf = (unsigned*)(base + o_hsA);  // alias (dead after build_kernel, before xconv)
    int* colx  = (int*)(base + o_colx);
    int* rowp  = (int*)(base + o_rowp);
    float* dinv = (float*)(base + o_dinv);
    int* bcnt  = (int*)(base + o_bcnt);
    int* boff  = (int*)(base + o_boff);
    int* bcur  = (int*)(base + o_bcur);
    u16* wbt   = (u16*)(base + o_wbt);

    int nchunk = (E + 4095) / 4096;

    wconv_kernel<<<194, 256, 0, stream>>>(W1, W2, W3, wbt,
                                          (unsigned*)(hsB + (size_t)N * FDIM), bcnt, NB);
    count_kernel<<<nchunk, 256, 0, stream>>>(dst, E, bcnt, NB);
    scan_kernel<<<1, 512, 0, stream>>>(bcnt, NB, E, boff, bcur);
    part_kernel<<<nchunk, 256, 0, stream>>>(src, dst, E, bcur, ebuf, NB);
    build_kernel<<<NB, 256, 0, stream>>>(ebuf, boff, rowp, dinv, colx, N, E);
    xconv_kernel<<<(((N + 1) * FDIM / 4) + 255) / 256, 256, 0, stream>>>(x, dinv, hsA, N);

    int aggBlocks = (N + 3) / 4;
    int gemmBlocks = (N + 63) / 64;

    // L1: hsA -> agg -> hsB; in-place gemm on hsB (-> pre-scaled h1 table)
    agg_kernel<<<aggBlocks, 256, 0, stream>>>(hsA, dinv, rowp, colx, hsB, N);
    gemm_mfma_kernel<true><<<gemmBlocks, 256, 0, stream>>>(hsB, wbt, b1, dinv, N);
    // L2: hsB -> agg -> hsA; in-place gemm on hsA (-> pre-scaled h2 table)
    agg_kernel<<<aggBlocks, 256, 0, stream>>>(hsB, dinv, rowp, colx, hsA, N);
    gemm_mfma_kernel<true><<<gemmBlocks, 256, 0, stream>>>(hsA, wbt + 16384, b2, dinv, N);
    // L3: hsA -> agg -> hsB; in-place gemm on hsB (unscaled h3)
    agg_kernel<<<aggBlocks, 256, 0, stream>>>(hsA, dinv, rowp, colx, hsB, N);
    gemm_mfma_kernel<false><<<gemmBlocks, 256, 0, stream>>>(hsB, wbt + 32768, b3, dinv, N);

    pool_head_kernel<<<G, 512, 0, stream>>>(hsB, batch, N, Wo, bo, (float*)d_out, G);
}